// Round 3
// baseline (540.862 us; speedup 1.0000x reference)
//
#include <hip/hip_runtime.h>
#include <stdint.h>

// ---------------------------------------------------------------------------
// MambaLikeBlock on MI355X (gfx950)
//   LN1 -> [u|gate] GEMM (bf16 MFMA) -> blocked bidirectional IIR scan ->
//   W_out GEMM (+residual) -> LN2 -> FF1 GEMM (silu) -> FF2 GEMM (+residual)
// Workspace budget: ~109 MB (R1 33.5 + R2/R3 67 + weights/carries ~8.5),
// via liveness aliasing: R1 = hidden->state->hbuf; R2+R3 = u|gate -> ffb.
// u is stored bf16 (scan accumulates fp32 in registers; error << threshold).
// ---------------------------------------------------------------------------

#define L_SEQ 32768
#define CDIM 512
#define LN_EPS 1e-5f
#define CHUNK 64
#define NCHUNK (L_SEQ / CHUNK) // 512

typedef __attribute__((ext_vector_type(8))) short short8;
typedef __attribute__((ext_vector_type(4))) float floatx4;

__device__ inline unsigned short f2bf(float f) {
  union { float f; unsigned int u; } v; v.f = f;
  unsigned int r = v.u + 0x7fffu + ((v.u >> 16) & 1u);
  return (unsigned short)(r >> 16);
}
__device__ inline float bf2f(unsigned short h) {
  union { float f; unsigned int u; } v; v.u = ((unsigned int)h) << 16;
  return v.f;
}
__device__ inline float sigmoidf_(float x) { return 1.0f / (1.0f + __expf(-x)); }

__device__ inline void async16(const void* g, void* l) {
  __builtin_amdgcn_global_load_lds(
      (const __attribute__((address_space(1))) unsigned int*)g,
      (__attribute__((address_space(3))) unsigned int*)l, 16, 0, 0);
}

// ---------------- LayerNorm: one wave per row (C=512 = 64 lanes x 8) -------
__global__ __launch_bounds__(256) void ln_kernel(const float* __restrict__ x,
    const float* __restrict__ w, const float* __restrict__ b,
    unsigned short* __restrict__ out) {
  int row = blockIdx.x * 4 + (threadIdx.x >> 6);
  int lane = threadIdx.x & 63;
  const float4* xr = (const float4*)(x + (size_t)row * CDIM);
  float4 v0 = xr[lane * 2];
  float4 v1 = xr[lane * 2 + 1];
  float s = v0.x + v0.y + v0.z + v0.w + v1.x + v1.y + v1.z + v1.w;
  float s2 = v0.x * v0.x + v0.y * v0.y + v0.z * v0.z + v0.w * v0.w +
             v1.x * v1.x + v1.y * v1.y + v1.z * v1.z + v1.w * v1.w;
  for (int m = 32; m > 0; m >>= 1) {
    s += __shfl_xor(s, m, 64);
    s2 += __shfl_xor(s2, m, 64);
  }
  float mean = s * (1.0f / CDIM);
  float var = s2 * (1.0f / CDIM) - mean * mean;
  float rs = rsqrtf(var + LN_EPS);
  const float4* wr = (const float4*)w;
  const float4* br = (const float4*)b;
  float4 w0 = wr[lane * 2], w1 = wr[lane * 2 + 1];
  float4 b0 = br[lane * 2], b1 = br[lane * 2 + 1];
  unsigned int p0 = (unsigned int)f2bf((v0.x - mean) * rs * w0.x + b0.x) |
                    ((unsigned int)f2bf((v0.y - mean) * rs * w0.y + b0.y) << 16);
  unsigned int p1 = (unsigned int)f2bf((v0.z - mean) * rs * w0.z + b0.z) |
                    ((unsigned int)f2bf((v0.w - mean) * rs * w0.w + b0.w) << 16);
  unsigned int p2 = (unsigned int)f2bf((v1.x - mean) * rs * w1.x + b1.x) |
                    ((unsigned int)f2bf((v1.y - mean) * rs * w1.y + b1.y) << 16);
  unsigned int p3 = (unsigned int)f2bf((v1.z - mean) * rs * w1.z + b1.z) |
                    ((unsigned int)f2bf((v1.w - mean) * rs * w1.w + b1.w) << 16);
  uint4 pk; pk.x = p0; pk.y = p1; pk.z = p2; pk.w = p3;
  *((uint4*)(out + (size_t)row * CDIM + lane * 8)) = pk;
}

// ---------------- Weight transpose fp32 KxN -> bf16 NxK --------------------
__global__ __launch_bounds__(256) void transpose_w(const float* __restrict__ W,
    unsigned short* __restrict__ Wt, int K, int N) {
  __shared__ float tile[32][33];
  int n0 = blockIdx.x * 32, k0 = blockIdx.y * 32;
  int tx = threadIdx.x & 31, ty = threadIdx.x >> 5; // 32x8
  for (int r = 0; r < 32; r += 8)
    tile[ty + r][tx] = W[(size_t)(k0 + ty + r) * N + n0 + tx];
  __syncthreads();
  for (int r = 0; r < 32; r += 8)
    Wt[(size_t)(n0 + ty + r) * K + k0 + tx] = f2bf(tile[tx][ty + r]);
}

// ---------------- decay prep: sigmoid + d^CHUNK ----------------------------
__global__ void decay_prep(const float* __restrict__ logit,
    float* __restrict__ decay, float* __restrict__ decayT) {
  int c = threadIdx.x; // 512 threads
  float d = sigmoidf_(logit[c]);
  decay[c] = d;
  float p = d;
  for (int i = 0; i < 6; i++) p *= p; // d^64 (CHUNK=64=2^6)
  decayT[c] = p;
}

// ---------------- bf16 MFMA GEMM: C = A(MxK) * Bt(NxK)^T + epilogue --------
// EPI 0: n<512 -> outU(bf16) = v+biasA[n]; n>=512 -> outG(bf16)=sigmoid(v+biasB)
// EPI 1: outF = res + v + biasA[n]           (float out)
// EPI 2: outG = bf16(silu(v + biasA[n]))     (bf16 out)
template <int EPI>
__global__ __launch_bounds__(256) void gemm_bt(
    const unsigned short* __restrict__ A, const unsigned short* __restrict__ Bt,
    const float* __restrict__ biasA, const float* __restrict__ biasB,
    const float* __restrict__ res, float* __restrict__ outF,
    unsigned short* __restrict__ outU, unsigned short* __restrict__ outG,
    int M, int N, int K) {
  __shared__ unsigned short As[128 * 32];
  __shared__ unsigned short Bs[128 * 32];
  int bn = blockIdx.x * 128, bm = blockIdx.y * 128;
  int tid = threadIdx.x, wave = tid >> 6, lane = tid & 63;
  int wm = (wave >> 1) * 64, wn = (wave & 1) * 64;

  // staging: LDS byte ofs = half*4096 + wave*1024 + lane*16
  int srow = wave * 16 + (lane >> 2);
  int scol = (lane & 3) * 8;
  const unsigned short* aP0 = A + (size_t)(bm + srow) * K + scol;
  const unsigned short* aP1 = A + (size_t)(bm + 64 + srow) * K + scol;
  const unsigned short* bP0 = Bt + (size_t)(bn + srow) * K + scol;
  const unsigned short* bP1 = Bt + (size_t)(bn + 64 + srow) * K + scol;
  unsigned short* As0 = As + wave * 512;
  unsigned short* As1 = As + 2048 + wave * 512;
  unsigned short* Bs0 = Bs + wave * 512;
  unsigned short* Bs1 = Bs + 2048 + wave * 512;

  floatx4 acc[4][4];
#pragma unroll
  for (int i = 0; i < 4; i++)
#pragma unroll
    for (int j = 0; j < 4; j++) acc[i][j] = (floatx4){0.f, 0.f, 0.f, 0.f};

  int quad = lane >> 4, r16 = lane & 15;

  for (int k0 = 0; k0 < K; k0 += 32) {
    async16(aP0 + k0, As0);
    async16(aP1 + k0, As1);
    async16(bP0 + k0, Bs0);
    async16(bP1 + k0, Bs1);
    __syncthreads();
    short8 af[4], bfm[4];
#pragma unroll
    for (int i = 0; i < 4; i++)
      af[i] = *(const short8*)(As + (wm + i * 16 + r16) * 32 + quad * 8);
#pragma unroll
    for (int j = 0; j < 4; j++)
      bfm[j] = *(const short8*)(Bs + (wn + j * 16 + r16) * 32 + quad * 8);
#pragma unroll
    for (int i = 0; i < 4; i++)
#pragma unroll
      for (int j = 0; j < 4; j++)
        acc[i][j] = __builtin_amdgcn_mfma_f32_16x16x32_bf16(af[i], bfm[j], acc[i][j], 0, 0, 0);
    __syncthreads();
  }

#pragma unroll
  for (int j = 0; j < 4; j++) {
    int n = bn + wn + j * 16 + r16;
#pragma unroll
    for (int i = 0; i < 4; i++) {
      int mb = bm + wm + i * 16 + quad * 4;
#pragma unroll
      for (int r = 0; r < 4; r++) {
        int m = mb + r;
        float v = acc[i][j][r];
        if (EPI == 0) {
          if (n < 512) {
            outU[(size_t)m * 512 + n] = f2bf(v + biasA[n]);
          } else {
            outG[(size_t)m * 512 + (n - 512)] = f2bf(sigmoidf_(v + biasB[n - 512]));
          }
        } else if (EPI == 1) {
          size_t idx = (size_t)m * N + n;
          outF[idx] = res[idx] + v + biasA[n];
        } else {
          float t = v + biasA[n];
          outG[(size_t)m * N + n] = f2bf(t * sigmoidf_(t));
        }
      }
    }
  }
}

// ---------------- Scan phase 1: per-chunk fwd/bwd aggregates ---------------
__global__ __launch_bounds__(512) void scan_phase1(const unsigned short* __restrict__ u,
    const float* __restrict__ decay, float* __restrict__ fa, float* __restrict__ ba) {
  int c = threadIdx.x, k = blockIdx.x;
  float d = decay[c];
  const unsigned short* up = u + (size_t)k * CHUNK * CDIM + c;
  float f = 0.f, bs = 0.f, p = 1.f;
#pragma unroll 8
  for (int t = 0; t < CHUNK; t++) {
    float v = bf2f(up[(size_t)t * CDIM]);
    f = d * f + v;
    bs += p * v;
    p *= d;
  }
  fa[(size_t)k * CDIM + c] = f;
  ba[(size_t)k * CDIM + c] = bs;
}

// ---------------- Scan phase 2: cross-chunk carries ------------------------
__global__ __launch_bounds__(256) void scan_phase2(const float* __restrict__ fa,
    const float* __restrict__ ba, const float* __restrict__ decayT,
    float* __restrict__ fc, float* __restrict__ bc) {
  int c = blockIdx.x * 256 + threadIdx.x;
  float dT = decayT[c];
  float run = 0.f;
#pragma unroll 8
  for (int k = 0; k < NCHUNK; k++) {
    fc[(size_t)k * CDIM + c] = run;
    run = dT * run + fa[(size_t)k * CDIM + c];
  }
  run = 0.f;
#pragma unroll 8
  for (int k = NCHUNK - 1; k >= 0; k--) {
    bc[(size_t)k * CDIM + c] = run;
    run = dT * run + ba[(size_t)k * CDIM + c];
  }
}

// ---------------- Scan phase 3: apply carries, combine, gate ---------------
__global__ __launch_bounds__(512) void scan_phase3(const unsigned short* __restrict__ u,
    const unsigned short* __restrict__ gate, const float* __restrict__ decay,
    const float* __restrict__ fc, const float* __restrict__ bc,
    unsigned short* __restrict__ state) {
  int c = threadIdx.x, k = blockIdx.x;
  float d = decay[c];
  size_t base = (size_t)k * CHUNK * CDIM + c;
  float fwd[CHUNK];
  float run = fc[(size_t)k * CDIM + c];
#pragma unroll
  for (int t = 0; t < CHUNK; t++) {
    run = d * run + bf2f(u[base + (size_t)t * CDIM]);
    fwd[t] = run;
  }
  float runb = bc[(size_t)k * CDIM + c];
#pragma unroll
  for (int t = CHUNK - 1; t >= 0; t--) {
    runb = d * runb + bf2f(u[base + (size_t)t * CDIM]);
    float g = bf2f(gate[base + (size_t)t * CDIM]);
    state[base + (size_t)t * CDIM] = f2bf(0.5f * (fwd[t] + runb) * g);
  }
}

// ---------------------------------------------------------------------------
extern "C" void kernel_launch(void* const* d_in, const int* in_sizes, int n_in,
                              void* d_out, int out_size, void* d_ws, size_t ws_size,
                              hipStream_t stream) {
  const float* x = (const float*)d_in[0];
  const float* ln1_w = (const float*)d_in[1];
  const float* ln1_b = (const float*)d_in[2];
  const float* W_in = (const float*)d_in[3];
  const float* b_in = (const float*)d_in[4];
  const float* W_gate = (const float*)d_in[5];
  const float* b_gate = (const float*)d_in[6];
  const float* W_out = (const float*)d_in[7];
  const float* b_out = (const float*)d_in[8];
  const float* decay_logit = (const float*)d_in[9];
  const float* ln2_w = (const float*)d_in[10];
  const float* ln2_b = (const float*)d_in[11];
  const float* W_ff1 = (const float*)d_in[12];
  const float* b_ff1 = (const float*)d_in[13];
  const float* W_ff2 = (const float*)d_in[14];
  const float* b_ff2 = (const float*)d_in[15];

  char* ws = (char*)d_ws;
  size_t off = 0;
  auto alloc = [&](size_t bytes) -> void* {
    void* p = ws + off;
    off += (bytes + 255) & ~(size_t)255;
    return p;
  };
  // --- small persistent buffers (~8.5 MB) ---
  unsigned short* Wt_ig  = (unsigned short*)alloc((size_t)1024 * 512 * 2);
  unsigned short* Wt_out = (unsigned short*)alloc((size_t)512 * 512 * 2);
  unsigned short* Wt_ff1 = (unsigned short*)alloc((size_t)1024 * 512 * 2);
  unsigned short* Wt_ff2 = (unsigned short*)alloc((size_t)512 * 1024 * 2);
  float* fa = (float*)alloc((size_t)NCHUNK * CDIM * 4);
  float* ba = (float*)alloc((size_t)NCHUNK * CDIM * 4);
  float* fc = (float*)alloc((size_t)NCHUNK * CDIM * 4);
  float* bc = (float*)alloc((size_t)NCHUNK * CDIM * 4);
  float* decay  = (float*)alloc(CDIM * 4);
  float* decayT = (float*)alloc(CDIM * 4);
  // --- large aliased regions (liveness-disjoint) ---
  const size_t LC2 = (size_t)L_SEQ * CDIM * 2; // 33.55 MB
  unsigned short* R1 = (unsigned short*)alloc(LC2);      // hidden -> state -> hbuf
  unsigned short* R2 = (unsigned short*)alloc(LC2);      // u(bf16) -> ffb[0:]
  unsigned short* R3 = (unsigned short*)alloc(LC2);      // gate    -> ffb[L*C:]
  unsigned short* hidden = R1;
  unsigned short* state  = R1;
  unsigned short* hbuf   = R1;
  unsigned short* u_buf  = R2;
  unsigned short* gate   = R3;
  unsigned short* ffb    = R2; // 67 MB spanning R2+R3 (contiguous)
  float* x2 = (float*)d_out;   // d_out doubles as x2 buffer

  // weight prep (bf16 transposed), decay
  transpose_w<<<dim3(16, 16), 256, 0, stream>>>(W_in, Wt_ig, 512, 512);
  transpose_w<<<dim3(16, 16), 256, 0, stream>>>(W_gate, Wt_ig + 512 * 512, 512, 512);
  transpose_w<<<dim3(16, 16), 256, 0, stream>>>(W_out, Wt_out, 512, 512);
  transpose_w<<<dim3(32, 16), 256, 0, stream>>>(W_ff1, Wt_ff1, 512, 1024);
  transpose_w<<<dim3(16, 32), 256, 0, stream>>>(W_ff2, Wt_ff2, 1024, 512);
  decay_prep<<<1, 512, 0, stream>>>(decay_logit, decay, decayT);

  // LN1
  ln_kernel<<<L_SEQ / 4, 256, 0, stream>>>(x, ln1_w, ln1_b, hidden);

  // u | gate fused GEMM (N=1024)
  gemm_bt<0><<<dim3(1024 / 128, L_SEQ / 128), 256, 0, stream>>>(
      hidden, Wt_ig, b_in, b_gate, nullptr, nullptr, u_buf, gate, L_SEQ, 1024, 512);

  // bidirectional scan
  scan_phase1<<<NCHUNK, 512, 0, stream>>>(u_buf, decay, fa, ba);
  scan_phase2<<<2, 256, 0, stream>>>(fa, ba, decayT, fc, bc);
  scan_phase3<<<NCHUNK, 512, 0, stream>>>(u_buf, gate, decay, fc, bc, state);

  // x2 = x + state @ W_out + b_out   (written to d_out)
  gemm_bt<1><<<dim3(512 / 128, L_SEQ / 128), 256, 0, stream>>>(
      state, Wt_out, b_out, nullptr, x, x2, nullptr, nullptr, L_SEQ, 512, 512);

  // LN2
  ln_kernel<<<L_SEQ / 4, 256, 0, stream>>>(x2, ln2_w, ln2_b, hbuf);

  // ff = silu(h @ W_ff1 + b_ff1)
  gemm_bt<2><<<dim3(1024 / 128, L_SEQ / 128), 256, 0, stream>>>(
      hbuf, Wt_ff1, b_ff1, nullptr, nullptr, nullptr, nullptr, ffb, L_SEQ, 1024, 512);

  // out = x2 + ff @ W_ff2 + b_ff2   (in-place read/write on d_out is per-element safe)
  gemm_bt<1><<<dim3(512 / 128, L_SEQ / 128), 256, 0, stream>>>(
      ffb, Wt_ff2, b_ff2, nullptr, x2, x2, nullptr, nullptr, L_SEQ, 512, 1024);
}

// Round 4
// 499.187 us; speedup vs baseline: 1.0835x; 1.0835x over previous
//
#include <hip/hip_runtime.h>
#include <stdint.h>

// ---------------------------------------------------------------------------
// MambaLikeBlock on MI355X (gfx950)
//   LN1 -> [u|gate] GEMM (bf16 MFMA) -> blocked bidirectional IIR scan ->
//   W_out GEMM (+residual) -> LN2 -> FF1 GEMM (silu) -> FF2 GEMM (+residual)
// R4: GEMM gets (a) double-buffered LDS prefetch with ONE barrier/iter,
//     (b) XCD-aware block remap (A-panel-sharing blocks -> same XCD L2),
//     (c) launch_bounds(256,3) for 3 blocks/CU.
// ---------------------------------------------------------------------------

#define L_SEQ 32768
#define CDIM 512
#define LN_EPS 1e-5f
#define CHUNK 64
#define NCHUNK (L_SEQ / CHUNK) // 512

typedef __attribute__((ext_vector_type(8))) short short8;
typedef __attribute__((ext_vector_type(4))) float floatx4;

__device__ inline unsigned short f2bf(float f) {
  union { float f; unsigned int u; } v; v.f = f;
  unsigned int r = v.u + 0x7fffu + ((v.u >> 16) & 1u);
  return (unsigned short)(r >> 16);
}
__device__ inline float bf2f(unsigned short h) {
  union { float f; unsigned int u; } v; v.u = ((unsigned int)h) << 16;
  return v.f;
}
__device__ inline float sigmoidf_(float x) { return 1.0f / (1.0f + __expf(-x)); }

__device__ inline void async16(const void* g, void* l) {
  __builtin_amdgcn_global_load_lds(
      (const __attribute__((address_space(1))) unsigned int*)g,
      (__attribute__((address_space(3))) unsigned int*)l, 16, 0, 0);
}

// ---------------- LayerNorm: one wave per row (C=512 = 64 lanes x 8) -------
__global__ __launch_bounds__(256) void ln_kernel(const float* __restrict__ x,
    const float* __restrict__ w, const float* __restrict__ b,
    unsigned short* __restrict__ out) {
  int row = blockIdx.x * 4 + (threadIdx.x >> 6);
  int lane = threadIdx.x & 63;
  const float4* xr = (const float4*)(x + (size_t)row * CDIM);
  float4 v0 = xr[lane * 2];
  float4 v1 = xr[lane * 2 + 1];
  float s = v0.x + v0.y + v0.z + v0.w + v1.x + v1.y + v1.z + v1.w;
  float s2 = v0.x * v0.x + v0.y * v0.y + v0.z * v0.z + v0.w * v0.w +
             v1.x * v1.x + v1.y * v1.y + v1.z * v1.z + v1.w * v1.w;
  for (int m = 32; m > 0; m >>= 1) {
    s += __shfl_xor(s, m, 64);
    s2 += __shfl_xor(s2, m, 64);
  }
  float mean = s * (1.0f / CDIM);
  float var = s2 * (1.0f / CDIM) - mean * mean;
  float rs = rsqrtf(var + LN_EPS);
  const float4* wr = (const float4*)w;
  const float4* br = (const float4*)b;
  float4 w0 = wr[lane * 2], w1 = wr[lane * 2 + 1];
  float4 b0 = br[lane * 2], b1 = br[lane * 2 + 1];
  unsigned int p0 = (unsigned int)f2bf((v0.x - mean) * rs * w0.x + b0.x) |
                    ((unsigned int)f2bf((v0.y - mean) * rs * w0.y + b0.y) << 16);
  unsigned int p1 = (unsigned int)f2bf((v0.z - mean) * rs * w0.z + b0.z) |
                    ((unsigned int)f2bf((v0.w - mean) * rs * w0.w + b0.w) << 16);
  unsigned int p2 = (unsigned int)f2bf((v1.x - mean) * rs * w1.x + b1.x) |
                    ((unsigned int)f2bf((v1.y - mean) * rs * w1.y + b1.y) << 16);
  unsigned int p3 = (unsigned int)f2bf((v1.z - mean) * rs * w1.z + b1.z) |
                    ((unsigned int)f2bf((v1.w - mean) * rs * w1.w + b1.w) << 16);
  uint4 pk; pk.x = p0; pk.y = p1; pk.z = p2; pk.w = p3;
  *((uint4*)(out + (size_t)row * CDIM + lane * 8)) = pk;
}

// ---------------- Weight transpose fp32 KxN -> bf16 NxK --------------------
__global__ __launch_bounds__(256) void transpose_w(const float* __restrict__ W,
    unsigned short* __restrict__ Wt, int K, int N) {
  __shared__ float tile[32][33];
  int n0 = blockIdx.x * 32, k0 = blockIdx.y * 32;
  int tx = threadIdx.x & 31, ty = threadIdx.x >> 5; // 32x8
  for (int r = 0; r < 32; r += 8)
    tile[ty + r][tx] = W[(size_t)(k0 + ty + r) * N + n0 + tx];
  __syncthreads();
  for (int r = 0; r < 32; r += 8)
    Wt[(size_t)(n0 + ty + r) * K + k0 + tx] = f2bf(tile[tx][ty + r]);
}

// ---------------- decay prep: sigmoid + d^CHUNK ----------------------------
__global__ void decay_prep(const float* __restrict__ logit,
    float* __restrict__ decay, float* __restrict__ decayT) {
  int c = threadIdx.x; // 512 threads
  float d = sigmoidf_(logit[c]);
  decay[c] = d;
  float p = d;
  for (int i = 0; i < 6; i++) p *= p; // d^64 (CHUNK=64=2^6)
  decayT[c] = p;
}

// ---------------- bf16 MFMA GEMM: C = A(MxK) * Bt(NxK)^T + epilogue --------
// EPI 0: n<512 -> outU(bf16) = v+biasA[n]; n>=512 -> outG(bf16)=sigmoid(v+biasB)
// EPI 1: outF = res + v + biasA[n]           (float out)
// EPI 2: outG = bf16(silu(v + biasA[n]))     (bf16 out)
template <int EPI>
__global__ __launch_bounds__(256, 3) void gemm_bt(
    const unsigned short* __restrict__ A, const unsigned short* __restrict__ Bt,
    const float* __restrict__ biasA, const float* __restrict__ biasB,
    const float* __restrict__ res, float* __restrict__ outF,
    unsigned short* __restrict__ outU, unsigned short* __restrict__ outG,
    int M, int N, int K) {
  __shared__ unsigned short As[2][128 * 32];
  __shared__ unsigned short Bs[2][128 * 32];

  // XCD-aware remap: grid = (M/128, N/128). Assume XCD = bid % 8.
  // Give each XCD a contiguous range of bm panels; iterate bn fastest so
  // blocks sharing an A panel run back-to-back on the same XCD L2.
  int nbx = gridDim.x, nby = gridDim.y;
  int bid = blockIdx.x + blockIdx.y * nbx;
  int per = (nbx * nby) >> 3;
  int w = (bid & 7) * per + (bid >> 3);
  int ni = w % nby;
  int mi = w / nby;
  int bm = mi << 7, bn = ni << 7;

  int tid = threadIdx.x, wave = tid >> 6, lane = tid & 63;
  int wm = (wave >> 1) * 64, wn = (wave & 1) * 64;

  // staging: each wave stages 16 rows of A-half / B-half per buffer
  int srow = wave * 16 + (lane >> 2);
  int scol = (lane & 3) * 8;
  const unsigned short* aP0 = A + (size_t)(bm + srow) * K + scol;
  const unsigned short* aP1 = A + (size_t)(bm + 64 + srow) * K + scol;
  const unsigned short* bP0 = Bt + (size_t)(bn + srow) * K + scol;
  const unsigned short* bP1 = Bt + (size_t)(bn + 64 + srow) * K + scol;

  floatx4 acc[4][4];
#pragma unroll
  for (int i = 0; i < 4; i++)
#pragma unroll
    for (int j = 0; j < 4; j++) acc[i][j] = (floatx4){0.f, 0.f, 0.f, 0.f};

  int quad = lane >> 4, r16 = lane & 15;

  // prologue: prefetch tile 0 into buffer 0
  async16(aP0, &As[0][wave * 512]);
  async16(aP1, &As[0][2048 + wave * 512]);
  async16(bP0, &Bs[0][wave * 512]);
  async16(bP1, &Bs[0][2048 + wave * 512]);

  for (int k0 = 0; k0 < K; k0 += 32) {
    int cur = (k0 >> 5) & 1, nxt = cur ^ 1;
    __syncthreads(); // drains prefetch of tile k0; also fences reads of buf nxt
    if (k0 + 32 < K) {
      async16(aP0 + k0 + 32, &As[nxt][wave * 512]);
      async16(aP1 + k0 + 32, &As[nxt][2048 + wave * 512]);
      async16(bP0 + k0 + 32, &Bs[nxt][wave * 512]);
      async16(bP1 + k0 + 32, &Bs[nxt][2048 + wave * 512]);
    }
    short8 af[4], bfm[4];
#pragma unroll
    for (int i = 0; i < 4; i++)
      af[i] = *(const short8*)(&As[cur][(wm + i * 16 + r16) * 32 + quad * 8]);
#pragma unroll
    for (int j = 0; j < 4; j++)
      bfm[j] = *(const short8*)(&Bs[cur][(wn + j * 16 + r16) * 32 + quad * 8]);
#pragma unroll
    for (int i = 0; i < 4; i++)
#pragma unroll
      for (int j = 0; j < 4; j++)
        acc[i][j] = __builtin_amdgcn_mfma_f32_16x16x32_bf16(af[i], bfm[j], acc[i][j], 0, 0, 0);
  }

#pragma unroll
  for (int j = 0; j < 4; j++) {
    int n = bn + wn + j * 16 + r16;
#pragma unroll
    for (int i = 0; i < 4; i++) {
      int mb = bm + wm + i * 16 + quad * 4;
#pragma unroll
      for (int r = 0; r < 4; r++) {
        int m = mb + r;
        float v = acc[i][j][r];
        if (EPI == 0) {
          if (n < 512) {
            outU[(size_t)m * 512 + n] = f2bf(v + biasA[n]);
          } else {
            outG[(size_t)m * 512 + (n - 512)] = f2bf(sigmoidf_(v + biasB[n - 512]));
          }
        } else if (EPI == 1) {
          size_t idx = (size_t)m * N + n;
          outF[idx] = res[idx] + v + biasA[n];
        } else {
          float t = v + biasA[n];
          outG[(size_t)m * N + n] = f2bf(t * sigmoidf_(t));
        }
      }
    }
  }
}

// ---------------- Scan phase 1: per-chunk fwd/bwd aggregates ---------------
__global__ __launch_bounds__(512) void scan_phase1(const unsigned short* __restrict__ u,
    const float* __restrict__ decay, float* __restrict__ fa, float* __restrict__ ba) {
  int c = threadIdx.x, k = blockIdx.x;
  float d = decay[c];
  const unsigned short* up = u + (size_t)k * CHUNK * CDIM + c;
  float f = 0.f, bs = 0.f, p = 1.f;
#pragma unroll 8
  for (int t = 0; t < CHUNK; t++) {
    float v = bf2f(up[(size_t)t * CDIM]);
    f = d * f + v;
    bs += p * v;
    p *= d;
  }
  fa[(size_t)k * CDIM + c] = f;
  ba[(size_t)k * CDIM + c] = bs;
}

// ---------------- Scan phase 2: cross-chunk carries ------------------------
__global__ __launch_bounds__(256) void scan_phase2(const float* __restrict__ fa,
    const float* __restrict__ ba, const float* __restrict__ decayT,
    float* __restrict__ fc, float* __restrict__ bc) {
  int c = blockIdx.x * 256 + threadIdx.x;
  float dT = decayT[c];
  float run = 0.f;
#pragma unroll 8
  for (int k = 0; k < NCHUNK; k++) {
    fc[(size_t)k * CDIM + c] = run;
    run = dT * run + fa[(size_t)k * CDIM + c];
  }
  run = 0.f;
#pragma unroll 8
  for (int k = NCHUNK - 1; k >= 0; k--) {
    bc[(size_t)k * CDIM + c] = run;
    run = dT * run + ba[(size_t)k * CDIM + c];
  }
}

// ---------------- Scan phase 3: apply carries, combine, gate ---------------
__global__ __launch_bounds__(512) void scan_phase3(const unsigned short* __restrict__ u,
    const unsigned short* __restrict__ gate, const float* __restrict__ decay,
    const float* __restrict__ fc, const float* __restrict__ bc,
    unsigned short* __restrict__ state) {
  int c = threadIdx.x, k = blockIdx.x;
  float d = decay[c];
  size_t base = (size_t)k * CHUNK * CDIM + c;
  float fwd[CHUNK];
  float run = fc[(size_t)k * CDIM + c];
#pragma unroll
  for (int t = 0; t < CHUNK; t++) {
    run = d * run + bf2f(u[base + (size_t)t * CDIM]);
    fwd[t] = run;
  }
  float runb = bc[(size_t)k * CDIM + c];
#pragma unroll
  for (int t = CHUNK - 1; t >= 0; t--) {
    runb = d * runb + bf2f(u[base + (size_t)t * CDIM]);
    float g = bf2f(gate[base + (size_t)t * CDIM]);
    state[base + (size_t)t * CDIM] = f2bf(0.5f * (fwd[t] + runb) * g);
  }
}

// ---------------------------------------------------------------------------
extern "C" void kernel_launch(void* const* d_in, const int* in_sizes, int n_in,
                              void* d_out, int out_size, void* d_ws, size_t ws_size,
                              hipStream_t stream) {
  const float* x = (const float*)d_in[0];
  const float* ln1_w = (const float*)d_in[1];
  const float* ln1_b = (const float*)d_in[2];
  const float* W_in = (const float*)d_in[3];
  const float* b_in = (const float*)d_in[4];
  const float* W_gate = (const float*)d_in[5];
  const float* b_gate = (const float*)d_in[6];
  const float* W_out = (const float*)d_in[7];
  const float* b_out = (const float*)d_in[8];
  const float* decay_logit = (const float*)d_in[9];
  const float* ln2_w = (const float*)d_in[10];
  const float* ln2_b = (const float*)d_in[11];
  const float* W_ff1 = (const float*)d_in[12];
  const float* b_ff1 = (const float*)d_in[13];
  const float* W_ff2 = (const float*)d_in[14];
  const float* b_ff2 = (const float*)d_in[15];

  char* ws = (char*)d_ws;
  size_t off = 0;
  auto alloc = [&](size_t bytes) -> void* {
    void* p = ws + off;
    off += (bytes + 255) & ~(size_t)255;
    return p;
  };
  // --- small persistent buffers (~8.5 MB) ---
  unsigned short* Wt_ig  = (unsigned short*)alloc((size_t)1024 * 512 * 2);
  unsigned short* Wt_out = (unsigned short*)alloc((size_t)512 * 512 * 2);
  unsigned short* Wt_ff1 = (unsigned short*)alloc((size_t)1024 * 512 * 2);
  unsigned short* Wt_ff2 = (unsigned short*)alloc((size_t)512 * 1024 * 2);
  float* fa = (float*)alloc((size_t)NCHUNK * CDIM * 4);
  float* ba = (float*)alloc((size_t)NCHUNK * CDIM * 4);
  float* fc = (float*)alloc((size_t)NCHUNK * CDIM * 4);
  float* bc = (float*)alloc((size_t)NCHUNK * CDIM * 4);
  float* decay  = (float*)alloc(CDIM * 4);
  float* decayT = (float*)alloc(CDIM * 4);
  // --- large aliased regions (liveness-disjoint) ---
  const size_t LC2 = (size_t)L_SEQ * CDIM * 2; // 33.55 MB
  unsigned short* R1 = (unsigned short*)alloc(LC2);      // hidden -> state -> hbuf
  unsigned short* R2 = (unsigned short*)alloc(LC2);      // u(bf16) -> ffb[0:]
  unsigned short* R3 = (unsigned short*)alloc(LC2);      // gate    -> ffb[L*C:]
  unsigned short* hidden = R1;
  unsigned short* state  = R1;
  unsigned short* hbuf   = R1;
  unsigned short* u_buf  = R2;
  unsigned short* gate   = R3;
  unsigned short* ffb    = R2; // 67 MB spanning R2+R3 (contiguous)
  float* x2 = (float*)d_out;   // d_out doubles as x2 buffer

  // weight prep (bf16 transposed), decay
  transpose_w<<<dim3(16, 16), 256, 0, stream>>>(W_in, Wt_ig, 512, 512);
  transpose_w<<<dim3(16, 16), 256, 0, stream>>>(W_gate, Wt_ig + 512 * 512, 512, 512);
  transpose_w<<<dim3(16, 16), 256, 0, stream>>>(W_out, Wt_out, 512, 512);
  transpose_w<<<dim3(32, 16), 256, 0, stream>>>(W_ff1, Wt_ff1, 512, 1024);
  transpose_w<<<dim3(16, 32), 256, 0, stream>>>(W_ff2, Wt_ff2, 1024, 512);
  decay_prep<<<1, 512, 0, stream>>>(decay_logit, decay, decayT);

  // LN1
  ln_kernel<<<L_SEQ / 4, 256, 0, stream>>>(x, ln1_w, ln1_b, hidden);

  // u | gate fused GEMM (N=1024); grid = (M/128, N/128)
  gemm_bt<0><<<dim3(L_SEQ / 128, 1024 / 128), 256, 0, stream>>>(
      hidden, Wt_ig, b_in, b_gate, nullptr, nullptr, u_buf, gate, L_SEQ, 1024, 512);

  // bidirectional scan
  scan_phase1<<<NCHUNK, 512, 0, stream>>>(u_buf, decay, fa, ba);
  scan_phase2<<<2, 256, 0, stream>>>(fa, ba, decayT, fc, bc);
  scan_phase3<<<NCHUNK, 512, 0, stream>>>(u_buf, gate, decay, fc, bc, state);

  // x2 = x + state @ W_out + b_out   (written to d_out)
  gemm_bt<1><<<dim3(L_SEQ / 128, 512 / 128), 256, 0, stream>>>(
      state, Wt_out, b_out, nullptr, x, x2, nullptr, nullptr, L_SEQ, 512, 512);

  // LN2
  ln_kernel<<<L_SEQ / 4, 256, 0, stream>>>(x2, ln2_w, ln2_b, hbuf);

  // ff = silu(h @ W_ff1 + b_ff1)
  gemm_bt<2><<<dim3(L_SEQ / 128, 1024 / 128), 256, 0, stream>>>(
      hbuf, Wt_ff1, b_ff1, nullptr, nullptr, nullptr, nullptr, ffb, L_SEQ, 1024, 512);

  // out = x2 + ff @ W_ff2 + b_ff2   (in-place read/write on d_out is per-element safe)
  gemm_bt<1><<<dim3(L_SEQ / 128, 512 / 128), 256, 0, stream>>>(
      ffb, Wt_ff2, b_ff2, nullptr, x2, x2, nullptr, nullptr, L_SEQ, 512, 1024);
}

// Round 5
// 496.435 us; speedup vs baseline: 1.0895x; 1.0055x over previous
//
#include <hip/hip_runtime.h>
#include <stdint.h>

// ---------------------------------------------------------------------------
// MambaLikeBlock on MI355X (gfx950)
// R5: (a) bf16 epilogues staged through LDS -> fully coalesced 16B/lane
//     stores (kills 2.2x HBM write amplification seen in R4 WRITE_SIZE);
//     (b) XOR k-chunk swizzle on LDS staging/fragment reads (kills the
//     4.2M/dispatch SQ_LDS_BANK_CONFLICT); (c) launch_bounds(256,4).
// ---------------------------------------------------------------------------

#define L_SEQ 32768
#define CDIM 512
#define LN_EPS 1e-5f
#define CHUNK 64
#define NCHUNK (L_SEQ / CHUNK) // 512

typedef __attribute__((ext_vector_type(8))) short short8;
typedef __attribute__((ext_vector_type(4))) float floatx4;

__device__ inline unsigned short f2bf(float f) {
  union { float f; unsigned int u; } v; v.f = f;
  unsigned int r = v.u + 0x7fffu + ((v.u >> 16) & 1u);
  return (unsigned short)(r >> 16);
}
__device__ inline float bf2f(unsigned short h) {
  union { float f; unsigned int u; } v; v.u = ((unsigned int)h) << 16;
  return v.f;
}
__device__ inline float sigmoidf_(float x) { return 1.0f / (1.0f + __expf(-x)); }

__device__ inline void async16(const void* g, void* l) {
  __builtin_amdgcn_global_load_lds(
      (const __attribute__((address_space(1))) unsigned int*)g,
      (__attribute__((address_space(3))) unsigned int*)l, 16, 0, 0);
}

// ---------------- LayerNorm: one wave per row (C=512 = 64 lanes x 8) -------
__global__ __launch_bounds__(256) void ln_kernel(const float* __restrict__ x,
    const float* __restrict__ w, const float* __restrict__ b,
    unsigned short* __restrict__ out) {
  int row = blockIdx.x * 4 + (threadIdx.x >> 6);
  int lane = threadIdx.x & 63;
  const float4* xr = (const float4*)(x + (size_t)row * CDIM);
  float4 v0 = xr[lane * 2];
  float4 v1 = xr[lane * 2 + 1];
  float s = v0.x + v0.y + v0.z + v0.w + v1.x + v1.y + v1.z + v1.w;
  float s2 = v0.x * v0.x + v0.y * v0.y + v0.z * v0.z + v0.w * v0.w +
             v1.x * v1.x + v1.y * v1.y + v1.z * v1.z + v1.w * v1.w;
  for (int m = 32; m > 0; m >>= 1) {
    s += __shfl_xor(s, m, 64);
    s2 += __shfl_xor(s2, m, 64);
  }
  float mean = s * (1.0f / CDIM);
  float var = s2 * (1.0f / CDIM) - mean * mean;
  float rs = rsqrtf(var + LN_EPS);
  const float4* wr = (const float4*)w;
  const float4* br = (const float4*)b;
  float4 w0 = wr[lane * 2], w1 = wr[lane * 2 + 1];
  float4 b0 = br[lane * 2], b1 = br[lane * 2 + 1];
  unsigned int p0 = (unsigned int)f2bf((v0.x - mean) * rs * w0.x + b0.x) |
                    ((unsigned int)f2bf((v0.y - mean) * rs * w0.y + b0.y) << 16);
  unsigned int p1 = (unsigned int)f2bf((v0.z - mean) * rs * w0.z + b0.z) |
                    ((unsigned int)f2bf((v0.w - mean) * rs * w0.w + b0.w) << 16);
  unsigned int p2 = (unsigned int)f2bf((v1.x - mean) * rs * w1.x + b1.x) |
                    ((unsigned int)f2bf((v1.y - mean) * rs * w1.y + b1.y) << 16);
  unsigned int p3 = (unsigned int)f2bf((v1.z - mean) * rs * w1.z + b1.z) |
                    ((unsigned int)f2bf((v1.w - mean) * rs * w1.w + b1.w) << 16);
  uint4 pk; pk.x = p0; pk.y = p1; pk.z = p2; pk.w = p3;
  *((uint4*)(out + (size_t)row * CDIM + lane * 8)) = pk;
}

// ---------------- Weight transpose fp32 KxN -> bf16 NxK --------------------
__global__ __launch_bounds__(256) void transpose_w(const float* __restrict__ W,
    unsigned short* __restrict__ Wt, int K, int N) {
  __shared__ float tile[32][33];
  int n0 = blockIdx.x * 32, k0 = blockIdx.y * 32;
  int tx = threadIdx.x & 31, ty = threadIdx.x >> 5; // 32x8
  for (int r = 0; r < 32; r += 8)
    tile[ty + r][tx] = W[(size_t)(k0 + ty + r) * N + n0 + tx];
  __syncthreads();
  for (int r = 0; r < 32; r += 8)
    Wt[(size_t)(n0 + ty + r) * K + k0 + tx] = f2bf(tile[tx][ty + r]);
}

// ---------------- decay prep: sigmoid + d^CHUNK ----------------------------
__global__ void decay_prep(const float* __restrict__ logit,
    float* __restrict__ decay, float* __restrict__ decayT) {
  int c = threadIdx.x; // 512 threads
  float d = sigmoidf_(logit[c]);
  decay[c] = d;
  float p = d;
  for (int i = 0; i < 6; i++) p *= p; // d^64 (CHUNK=64=2^6)
  decayT[c] = p;
}

// ---------------- bf16 MFMA GEMM: C = A(MxK) * Bt(NxK)^T + epilogue --------
// EPI 0: n<512 -> outU(bf16) = v+biasA[n]; n>=512 -> outG(bf16)=sigmoid(v+biasB)
// EPI 1: outF = res + v + biasA[n]           (float out, direct stores)
// EPI 2: outG = bf16(silu(v + biasA[n]))     (bf16 out, staged)
template <int EPI>
__global__ __launch_bounds__(256, 4) void gemm_bt(
    const unsigned short* __restrict__ A, const unsigned short* __restrict__ Bt,
    const float* __restrict__ biasA, const float* __restrict__ biasB,
    const float* __restrict__ res, float* __restrict__ outF,
    unsigned short* __restrict__ outU, unsigned short* __restrict__ outG,
    int M, int N, int K) {
  // 34 KB shared: K-loop staging (32 KB) aliased with bf16 epilogue tile
  // (128 rows x 132 stride x 2B = 33792 B; stride 132 -> quad rows land on
  // disjoint bank octets).
  __shared__ char smemRaw[34048];
  unsigned short* As = (unsigned short*)smemRaw;            // [2][4096]
  unsigned short* Bs = (unsigned short*)(smemRaw + 16384);  // [2][4096]

  // XCD-aware remap: grid = (M/128, N/128); XCD = bid % 8. Blocks sharing an
  // A panel run consecutively on the same XCD (bn fastest within an XCD).
  int nbx = gridDim.x, nby = gridDim.y;
  int bid = blockIdx.x + blockIdx.y * nbx;
  int per = (nbx * nby) >> 3;
  int w = (bid & 7) * per + (bid >> 3);
  int ni = w % nby;
  int mi = w / nby;
  int bm = mi << 7, bn = ni << 7;

  int tid = threadIdx.x, wave = tid >> 6, lane = tid & 63;
  int wm = (wave >> 1) * 64, wn = (wave & 1) * 64;

  // staging with XOR chunk swizzle: lane l fetches row l>>2, k-chunk
  // (l&3)^((l>>3)&3); LDS dest is the fixed lane*16 slot.
  int srow = wave * 16 + (lane >> 2);
  int chunkSel = (lane & 3) ^ ((lane >> 3) & 3);
  int scol = chunkSel * 8;
  const unsigned short* aP0 = A + (size_t)(bm + srow) * K + scol;
  const unsigned short* aP1 = A + (size_t)(bm + 64 + srow) * K + scol;
  const unsigned short* bP0 = Bt + (size_t)(bn + srow) * K + scol;
  const unsigned short* bP1 = Bt + (size_t)(bn + 64 + srow) * K + scol;

  floatx4 acc[4][4];
#pragma unroll
  for (int i = 0; i < 4; i++)
#pragma unroll
    for (int j = 0; j < 4; j++) acc[i][j] = (floatx4){0.f, 0.f, 0.f, 0.f};

  int quad = lane >> 4, r16 = lane & 15;
  // fragment-read chunk slot (inverse of the staging swizzle), loop-invariant
  int cSwz = ((quad ^ (r16 >> 1)) & 3) * 8;

  // prologue: prefetch tile 0 into buffer 0
  async16(aP0, &As[wave * 512]);
  async16(aP1, &As[2048 + wave * 512]);
  async16(bP0, &Bs[wave * 512]);
  async16(bP1, &Bs[2048 + wave * 512]);

  for (int k0 = 0; k0 < K; k0 += 32) {
    int cur = ((k0 >> 5) & 1) * 4096, nxt = cur ^ 4096;
    __syncthreads(); // drains prefetch of tile k0; fences reads of buf nxt
    if (k0 + 32 < K) {
      async16(aP0 + k0 + 32, &As[nxt + wave * 512]);
      async16(aP1 + k0 + 32, &As[nxt + 2048 + wave * 512]);
      async16(bP0 + k0 + 32, &Bs[nxt + wave * 512]);
      async16(bP1 + k0 + 32, &Bs[nxt + 2048 + wave * 512]);
    }
    short8 af[4], bfm[4];
#pragma unroll
    for (int i = 0; i < 4; i++)
      af[i] = *(const short8*)(&As[cur + (wm + i * 16 + r16) * 32 + cSwz]);
#pragma unroll
    for (int j = 0; j < 4; j++)
      bfm[j] = *(const short8*)(&Bs[cur + (wn + j * 16 + r16) * 32 + cSwz]);
#pragma unroll
    for (int i = 0; i < 4; i++)
#pragma unroll
      for (int j = 0; j < 4; j++)
        acc[i][j] = __builtin_amdgcn_mfma_f32_16x16x32_bf16(af[i], bfm[j], acc[i][j], 0, 0, 0);
  }

  if (EPI == 1) {
    // fp32 output: 16 lanes x 4B = 64B aligned segments, no staging needed
#pragma unroll
    for (int j = 0; j < 4; j++) {
      int n = bn + wn + j * 16 + r16;
#pragma unroll
      for (int i = 0; i < 4; i++) {
        int mb = bm + wm + i * 16 + quad * 4;
#pragma unroll
        for (int r = 0; r < 4; r++) {
          size_t idx = (size_t)(mb + r) * N + n;
          outF[idx] = res[idx] + acc[i][j][r] + biasA[n];
        }
      }
    }
  } else {
    // bf16 output: stage tile in LDS, then coalesced 16B/lane stores
    unsigned short* sm = (unsigned short*)smemRaw;
    __syncthreads(); // all K-loop LDS reads done before overwrite
#pragma unroll
    for (int j = 0; j < 4; j++) {
      int n = bn + wn + j * 16 + r16;
      int ln = wn + j * 16 + r16;
#pragma unroll
      for (int i = 0; i < 4; i++) {
        int lmb = wm + i * 16 + quad * 4;
#pragma unroll
        for (int r = 0; r < 4; r++) {
          float v = acc[i][j][r];
          float t;
          if (EPI == 0) {
            t = (n < 512) ? (v + biasA[n]) : sigmoidf_(v + biasB[n - 512]);
          } else { // EPI == 2
            float z = v + biasA[n];
            t = z * sigmoidf_(z);
          }
          sm[(lmb + r) * 132 + ln] = f2bf(t);
        }
      }
    }
    __syncthreads();
    int row = tid >> 1, half = tid & 1;
    const unsigned short* src = sm + row * 132 + half * 64;
    unsigned short* gptr;
    if (EPI == 0) {
      gptr = ((bn < 512) ? outU : (outG - 512)) + (size_t)(bm + row) * 512 + bn + half * 64;
    } else {
      gptr = outG + (size_t)(bm + row) * N + bn + half * 64;
    }
#pragma unroll
    for (int s = 0; s < 8; s++)
      *(short8*)(gptr + s * 8) = *(const short8*)(src + s * 8);
  }
}

// ---------------- Scan phase 1: per-chunk fwd/bwd aggregates ---------------
__global__ __launch_bounds__(512) void scan_phase1(const unsigned short* __restrict__ u,
    const float* __restrict__ decay, float* __restrict__ fa, float* __restrict__ ba) {
  int c = threadIdx.x, k = blockIdx.x;
  float d = decay[c];
  const unsigned short* up = u + (size_t)k * CHUNK * CDIM + c;
  float f = 0.f, bs = 0.f, p = 1.f;
#pragma unroll 8
  for (int t = 0; t < CHUNK; t++) {
    float v = bf2f(up[(size_t)t * CDIM]);
    f = d * f + v;
    bs += p * v;
    p *= d;
  }
  fa[(size_t)k * CDIM + c] = f;
  ba[(size_t)k * CDIM + c] = bs;
}

// ---------------- Scan phase 2: cross-chunk carries ------------------------
__global__ __launch_bounds__(256) void scan_phase2(const float* __restrict__ fa,
    const float* __restrict__ ba, const float* __restrict__ decayT,
    float* __restrict__ fc, float* __restrict__ bc) {
  int c = blockIdx.x * 256 + threadIdx.x;
  float dT = decayT[c];
  float run = 0.f;
#pragma unroll 8
  for (int k = 0; k < NCHUNK; k++) {
    fc[(size_t)k * CDIM + c] = run;
    run = dT * run + fa[(size_t)k * CDIM + c];
  }
  run = 0.f;
#pragma unroll 8
  for (int k = NCHUNK - 1; k >= 0; k--) {
    bc[(size_t)k * CDIM + c] = run;
    run = dT * run + ba[(size_t)k * CDIM + c];
  }
}

// ---------------- Scan phase 3: apply carries, combine, gate ---------------
__global__ __launch_bounds__(512) void scan_phase3(const unsigned short* __restrict__ u,
    const unsigned short* __restrict__ gate, const float* __restrict__ decay,
    const float* __restrict__ fc, const float* __restrict__ bc,
    unsigned short* __restrict__ state) {
  int c = threadIdx.x, k = blockIdx.x;
  float d = decay[c];
  size_t base = (size_t)k * CHUNK * CDIM + c;
  float fwd[CHUNK];
  float run = fc[(size_t)k * CDIM + c];
#pragma unroll
  for (int t = 0; t < CHUNK; t++) {
    run = d * run + bf2f(u[base + (size_t)t * CDIM]);
    fwd[t] = run;
  }
  float runb = bc[(size_t)k * CDIM + c];
#pragma unroll
  for (int t = CHUNK - 1; t >= 0; t--) {
    runb = d * runb + bf2f(u[base + (size_t)t * CDIM]);
    float g = bf2f(gate[base + (size_t)t * CDIM]);
    state[base + (size_t)t * CDIM] = f2bf(0.5f * (fwd[t] + runb) * g);
  }
}

// ---------------------------------------------------------------------------
extern "C" void kernel_launch(void* const* d_in, const int* in_sizes, int n_in,
                              void* d_out, int out_size, void* d_ws, size_t ws_size,
                              hipStream_t stream) {
  const float* x = (const float*)d_in[0];
  const float* ln1_w = (const float*)d_in[1];
  const float* ln1_b = (const float*)d_in[2];
  const float* W_in = (const float*)d_in[3];
  const float* b_in = (const float*)d_in[4];
  const float* W_gate = (const float*)d_in[5];
  const float* b_gate = (const float*)d_in[6];
  const float* W_out = (const float*)d_in[7];
  const float* b_out = (const float*)d_in[8];
  const float* decay_logit = (const float*)d_in[9];
  const float* ln2_w = (const float*)d_in[10];
  const float* ln2_b = (const float*)d_in[11];
  const float* W_ff1 = (const float*)d_in[12];
  const float* b_ff1 = (const float*)d_in[13];
  const float* W_ff2 = (const float*)d_in[14];
  const float* b_ff2 = (const float*)d_in[15];

  char* ws = (char*)d_ws;
  size_t off = 0;
  auto alloc = [&](size_t bytes) -> void* {
    void* p = ws + off;
    off += (bytes + 255) & ~(size_t)255;
    return p;
  };
  // --- small persistent buffers (~8.5 MB) ---
  unsigned short* Wt_ig  = (unsigned short*)alloc((size_t)1024 * 512 * 2);
  unsigned short* Wt_out = (unsigned short*)alloc((size_t)512 * 512 * 2);
  unsigned short* Wt_ff1 = (unsigned short*)alloc((size_t)1024 * 512 * 2);
  unsigned short* Wt_ff2 = (unsigned short*)alloc((size_t)512 * 1024 * 2);
  float* fa = (float*)alloc((size_t)NCHUNK * CDIM * 4);
  float* ba = (float*)alloc((size_t)NCHUNK * CDIM * 4);
  float* fc = (float*)alloc((size_t)NCHUNK * CDIM * 4);
  float* bc = (float*)alloc((size_t)NCHUNK * CDIM * 4);
  float* decay  = (float*)alloc(CDIM * 4);
  float* decayT = (float*)alloc(CDIM * 4);
  // --- large aliased regions (liveness-disjoint) ---
  const size_t LC2 = (size_t)L_SEQ * CDIM * 2; // 33.55 MB
  unsigned short* R1 = (unsigned short*)alloc(LC2);      // hidden -> state -> hbuf
  unsigned short* R2 = (unsigned short*)alloc(LC2);      // u(bf16) -> ffb[0:]
  unsigned short* R3 = (unsigned short*)alloc(LC2);      // gate    -> ffb[L*C:]
  unsigned short* hidden = R1;
  unsigned short* state  = R1;
  unsigned short* hbuf   = R1;
  unsigned short* u_buf  = R2;
  unsigned short* gate   = R3;
  unsigned short* ffb    = R2; // 67 MB spanning R2+R3 (contiguous)
  float* x2 = (float*)d_out;   // d_out doubles as x2 buffer

  // weight prep (bf16 transposed), decay
  transpose_w<<<dim3(16, 16), 256, 0, stream>>>(W_in, Wt_ig, 512, 512);
  transpose_w<<<dim3(16, 16), 256, 0, stream>>>(W_gate, Wt_ig + 512 * 512, 512, 512);
  transpose_w<<<dim3(16, 16), 256, 0, stream>>>(W_out, Wt_out, 512, 512);
  transpose_w<<<dim3(32, 16), 256, 0, stream>>>(W_ff1, Wt_ff1, 512, 1024);
  transpose_w<<<dim3(16, 32), 256, 0, stream>>>(W_ff2, Wt_ff2, 1024, 512);
  decay_prep<<<1, 512, 0, stream>>>(decay_logit, decay, decayT);

  // LN1
  ln_kernel<<<L_SEQ / 4, 256, 0, stream>>>(x, ln1_w, ln1_b, hidden);

  // u | gate fused GEMM (N=1024); grid = (M/128, N/128)
  gemm_bt<0><<<dim3(L_SEQ / 128, 1024 / 128), 256, 0, stream>>>(
      hidden, Wt_ig, b_in, b_gate, nullptr, nullptr, u_buf, gate, L_SEQ, 1024, 512);

  // bidirectional scan
  scan_phase1<<<NCHUNK, 512, 0, stream>>>(u_buf, decay, fa, ba);
  scan_phase2<<<2, 256, 0, stream>>>(fa, ba, decayT, fc, bc);
  scan_phase3<<<NCHUNK, 512, 0, stream>>>(u_buf, gate, decay, fc, bc, state);

  // x2 = x + state @ W_out + b_out   (written to d_out)
  gemm_bt<1><<<dim3(L_SEQ / 128, 512 / 128), 256, 0, stream>>>(
      state, Wt_out, b_out, nullptr, x, x2, nullptr, nullptr, L_SEQ, 512, 512);

  // LN2
  ln_kernel<<<L_SEQ / 4, 256, 0, stream>>>(x2, ln2_w, ln2_b, hbuf);

  // ff = silu(h @ W_ff1 + b_ff1)
  gemm_bt<2><<<dim3(L_SEQ / 128, 1024 / 128), 256, 0, stream>>>(
      hbuf, Wt_ff1, b_ff1, nullptr, nullptr, nullptr, nullptr, ffb, L_SEQ, 1024, 512);

  // out = x2 + ff @ W_ff2 + b_ff2   (in-place read/write on d_out is per-element safe)
  gemm_bt<1><<<dim3(L_SEQ / 128, 512 / 128), 256, 0, stream>>>(
      ffb, Wt_ff2, b_ff2, nullptr, x2, x2, nullptr, nullptr, L_SEQ, 512, 1024);
}

// Round 6
// 483.953 us; speedup vs baseline: 1.1176x; 1.0258x over previous
//
#include <hip/hip_runtime.h>
#include <stdint.h>

// ---------------------------------------------------------------------------
// MambaLikeBlock on MI355X (gfx950)
// R6: (a) GEMM staging via VGPR round-trip (global_load->regs->ds_write):
//     plain loads aren't drained at s_barrier, so prefetch depth becomes
//     ~2 iterations instead of the 1-barrier cap of global_load_lds;
//     (b) all weight transposes + decay prep merged into ONE kernel launch.
// ---------------------------------------------------------------------------

#define L_SEQ 32768
#define CDIM 512
#define LN_EPS 1e-5f
#define CHUNK 64
#define NCHUNK (L_SEQ / CHUNK) // 512

typedef __attribute__((ext_vector_type(8))) short short8;
typedef __attribute__((ext_vector_type(4))) float floatx4;

__device__ inline unsigned short f2bf(float f) {
  union { float f; unsigned int u; } v; v.f = f;
  unsigned int r = v.u + 0x7fffu + ((v.u >> 16) & 1u);
  return (unsigned short)(r >> 16);
}
__device__ inline float bf2f(unsigned short h) {
  union { float f; unsigned int u; } v; v.u = ((unsigned int)h) << 16;
  return v.f;
}
__device__ inline float sigmoidf_(float x) { return 1.0f / (1.0f + __expf(-x)); }

// ---------------- LayerNorm: one wave per row (C=512 = 64 lanes x 8) -------
__global__ __launch_bounds__(256) void ln_kernel(const float* __restrict__ x,
    const float* __restrict__ w, const float* __restrict__ b,
    unsigned short* __restrict__ out) {
  int row = blockIdx.x * 4 + (threadIdx.x >> 6);
  int lane = threadIdx.x & 63;
  const float4* xr = (const float4*)(x + (size_t)row * CDIM);
  float4 v0 = xr[lane * 2];
  float4 v1 = xr[lane * 2 + 1];
  float s = v0.x + v0.y + v0.z + v0.w + v1.x + v1.y + v1.z + v1.w;
  float s2 = v0.x * v0.x + v0.y * v0.y + v0.z * v0.z + v0.w * v0.w +
             v1.x * v1.x + v1.y * v1.y + v1.z * v1.z + v1.w * v1.w;
  for (int m = 32; m > 0; m >>= 1) {
    s += __shfl_xor(s, m, 64);
    s2 += __shfl_xor(s2, m, 64);
  }
  float mean = s * (1.0f / CDIM);
  float var = s2 * (1.0f / CDIM) - mean * mean;
  float rs = rsqrtf(var + LN_EPS);
  const float4* wr = (const float4*)w;
  const float4* br = (const float4*)b;
  float4 w0 = wr[lane * 2], w1 = wr[lane * 2 + 1];
  float4 b0 = br[lane * 2], b1 = br[lane * 2 + 1];
  unsigned int p0 = (unsigned int)f2bf((v0.x - mean) * rs * w0.x + b0.x) |
                    ((unsigned int)f2bf((v0.y - mean) * rs * w0.y + b0.y) << 16);
  unsigned int p1 = (unsigned int)f2bf((v0.z - mean) * rs * w0.z + b0.z) |
                    ((unsigned int)f2bf((v0.w - mean) * rs * w0.w + b0.w) << 16);
  unsigned int p2 = (unsigned int)f2bf((v1.x - mean) * rs * w1.x + b1.x) |
                    ((unsigned int)f2bf((v1.y - mean) * rs * w1.y + b1.y) << 16);
  unsigned int p3 = (unsigned int)f2bf((v1.z - mean) * rs * w1.z + b1.z) |
                    ((unsigned int)f2bf((v1.w - mean) * rs * w1.w + b1.w) << 16);
  uint4 pk; pk.x = p0; pk.y = p1; pk.z = p2; pk.w = p3;
  *((uint4*)(out + (size_t)row * CDIM + lane * 8)) = pk;
}

// ---------------- Combined prep: 5 weight transposes + decay (1 launch) ----
__global__ __launch_bounds__(256) void prep_all(
    const float* __restrict__ W_in, const float* __restrict__ W_gate,
    const float* __restrict__ W_out, const float* __restrict__ W_ff1,
    const float* __restrict__ W_ff2, const float* __restrict__ logit,
    unsigned short* __restrict__ Wt_ig, unsigned short* __restrict__ Wt_out,
    unsigned short* __restrict__ Wt_ff1, unsigned short* __restrict__ Wt_ff2,
    float* __restrict__ decay, float* __restrict__ decayT) {
  int b = blockIdx.x;
  if (b >= 1792) { // decay prep
    for (int c = threadIdx.x; c < CDIM; c += 256) {
      float d = sigmoidf_(logit[c]);
      decay[c] = d;
      float p = d;
      for (int i = 0; i < 6; i++) p *= p; // d^64
      decayT[c] = p;
    }
    return;
  }
  const float* W; unsigned short* Wt; int Kd, Nd, t;
  if (b < 256)       { W = W_in;   Wt = Wt_ig;             Kd = 512;  Nd = 512;  t = b; }
  else if (b < 512)  { W = W_gate; Wt = Wt_ig + 512 * 512; Kd = 512;  Nd = 512;  t = b - 256; }
  else if (b < 768)  { W = W_out;  Wt = Wt_out;            Kd = 512;  Nd = 512;  t = b - 512; }
  else if (b < 1280) { W = W_ff1;  Wt = Wt_ff1;            Kd = 512;  Nd = 1024; t = b - 768; }
  else               { W = W_ff2;  Wt = Wt_ff2;            Kd = 1024; Nd = 512;  t = b - 1280; }
  int ntx = Nd >> 5;
  int n0 = (t % ntx) * 32, k0 = (t / ntx) * 32;
  __shared__ float tile[32][33];
  int tx = threadIdx.x & 31, ty = threadIdx.x >> 5; // 32x8
  for (int r = 0; r < 32; r += 8)
    tile[ty + r][tx] = W[(size_t)(k0 + ty + r) * Nd + n0 + tx];
  __syncthreads();
  for (int r = 0; r < 32; r += 8)
    Wt[(size_t)(n0 + ty + r) * Kd + k0 + tx] = f2bf(tile[tx][ty + r]);
}

// ---------------- bf16 MFMA GEMM: C = A(MxK) * Bt(NxK)^T + epilogue --------
// Staging: global_load (VGPR) -> ds_write, ping-pong reg sets p/q:
//   iter k: ds_read frags buf[k&1]; issue loads tile k+2 -> q; MFMA;
//           ds_write buf[(k+1)&1] <- p (tile k+1, ~2 iters in flight); barrier
// EPI 0: n<512 -> outU(bf16) = v+biasA[n]; n>=512 -> outG(bf16)=sigmoid(v+biasB)
// EPI 1: outF = res + v + biasA[n]           (float out, direct stores)
// EPI 2: outG = bf16(silu(v + biasA[n]))     (bf16 out, staged)
template <int EPI>
__global__ __launch_bounds__(256, 3) void gemm_bt(
    const unsigned short* __restrict__ A, const unsigned short* __restrict__ Bt,
    const float* __restrict__ biasA, const float* __restrict__ biasB,
    const float* __restrict__ res, float* __restrict__ outF,
    unsigned short* __restrict__ outU, unsigned short* __restrict__ outG,
    int M, int N, int K) {
  // 34 KB shared: K-loop staging (32 KB) aliased with bf16 epilogue tile.
  __shared__ char smemRaw[34048];
  unsigned short* As = (unsigned short*)smemRaw;            // 2 bufs x 4096 elems
  unsigned short* Bs = (unsigned short*)(smemRaw + 16384);  // 2 bufs x 4096 elems

  // XCD-aware remap: grid = (M/128, N/128); XCD = bid % 8. Blocks sharing an
  // A panel run consecutively on the same XCD (bn fastest within an XCD).
  int nbx = gridDim.x, nby = gridDim.y;
  int bid = blockIdx.x + blockIdx.y * nbx;
  int per = (nbx * nby) >> 3;
  int w = (bid & 7) * per + (bid >> 3);
  int ni = w % nby;
  int mi = w / nby;
  int bm = mi << 7, bn = ni << 7;

  int tid = threadIdx.x, wave = tid >> 6, lane = tid & 63;
  int wm = (wave >> 1) * 64, wn = (wave & 1) * 64;

  // staging addressing (same swizzled layout as R5; conflicts measured 0)
  int srow = wave * 16 + (lane >> 2);
  int chunkSel = (lane & 3) ^ ((lane >> 3) & 3);
  int scol = chunkSel * 8;
  const unsigned short* aP0 = A + (size_t)(bm + srow) * K + scol;
  const unsigned short* aP1 = A + (size_t)(bm + 64 + srow) * K + scol;
  const unsigned short* bP0 = Bt + (size_t)(bn + srow) * K + scol;
  const unsigned short* bP1 = Bt + (size_t)(bn + 64 + srow) * K + scol;
  int wslot = wave * 512 + lane * 8; // element offset within a 4096-elem buffer

  floatx4 acc[4][4];
#pragma unroll
  for (int i = 0; i < 4; i++)
#pragma unroll
    for (int j = 0; j < 4; j++) acc[i][j] = (floatx4){0.f, 0.f, 0.f, 0.f};

  int quad = lane >> 4, r16 = lane & 15;
  int cSwz = ((quad ^ (r16 >> 1)) & 3) * 8; // inverse of staging swizzle

  int NK = K >> 5;
  uint4 pa0, pa1, pb0, pb1;   // tile k+1 (to be ds_written this iter)
  uint4 qa0, qa1, qb0, qb1;   // tile k+2 (issued this iter)

  // prologue: tile 0 -> regs -> buf0; tile 1 -> p
  pa0 = *(const uint4*)(aP0);
  pa1 = *(const uint4*)(aP1);
  pb0 = *(const uint4*)(bP0);
  pb1 = *(const uint4*)(bP1);
  *(uint4*)&As[wslot]        = pa0;
  *(uint4*)&As[2048 + wslot] = pa1;
  *(uint4*)&Bs[wslot]        = pb0;
  *(uint4*)&Bs[2048 + wslot] = pb1;
  pa0 = *(const uint4*)(aP0 + 32);
  pa1 = *(const uint4*)(aP1 + 32);
  pb0 = *(const uint4*)(bP0 + 32);
  pb1 = *(const uint4*)(bP1 + 32);
  __syncthreads();

  for (int k = 0; k < NK; ++k) {
    int cur = (k & 1) * 4096, nxt = cur ^ 4096;
    short8 af[4], bfm[4];
#pragma unroll
    for (int i = 0; i < 4; i++)
      af[i] = *(const short8*)(&As[cur + (wm + i * 16 + r16) * 32 + cSwz]);
#pragma unroll
    for (int j = 0; j < 4; j++)
      bfm[j] = *(const short8*)(&Bs[cur + (wn + j * 16 + r16) * 32 + cSwz]);
    if (k + 2 < NK) { // issue loads for tile k+2 (2-iteration flight time)
      int o = (k + 2) * 32;
      qa0 = *(const uint4*)(aP0 + o);
      qa1 = *(const uint4*)(aP1 + o);
      qb0 = *(const uint4*)(bP0 + o);
      qb1 = *(const uint4*)(bP1 + o);
    }
#pragma unroll
    for (int i = 0; i < 4; i++)
#pragma unroll
      for (int j = 0; j < 4; j++)
        acc[i][j] = __builtin_amdgcn_mfma_f32_16x16x32_bf16(af[i], bfm[j], acc[i][j], 0, 0, 0);
    if (k + 1 < NK) { // stage tile k+1 (loaded ~2 iters ago) into nxt
      *(uint4*)&As[nxt + wslot]        = pa0;
      *(uint4*)&As[nxt + 2048 + wslot] = pa1;
      *(uint4*)&Bs[nxt + wslot]        = pb0;
      *(uint4*)&Bs[nxt + 2048 + wslot] = pb1;
    }
    __syncthreads();
    pa0 = qa0; pa1 = qa1; pb0 = qb0; pb1 = qb1;
  }

  if (EPI == 1) {
    // fp32 output: 16 lanes x 4B = 64B aligned segments, direct stores
#pragma unroll
    for (int j = 0; j < 4; j++) {
      int n = bn + wn + j * 16 + r16;
#pragma unroll
      for (int i = 0; i < 4; i++) {
        int mb = bm + wm + i * 16 + quad * 4;
#pragma unroll
        for (int r = 0; r < 4; r++) {
          size_t idx = (size_t)(mb + r) * N + n;
          outF[idx] = res[idx] + acc[i][j][r] + biasA[n];
        }
      }
    }
  } else {
    // bf16 output: stage tile in LDS, then coalesced 16B/lane stores
    unsigned short* sm = (unsigned short*)smemRaw;
#pragma unroll
    for (int j = 0; j < 4; j++) {
      int n = bn + wn + j * 16 + r16;
      int ln = wn + j * 16 + r16;
#pragma unroll
      for (int i = 0; i < 4; i++) {
        int lmb = wm + i * 16 + quad * 4;
#pragma unroll
        for (int r = 0; r < 4; r++) {
          float v = acc[i][j][r];
          float t;
          if (EPI == 0) {
            t = (n < 512) ? (v + biasA[n]) : sigmoidf_(v + biasB[n - 512]);
          } else { // EPI == 2
            float z = v + biasA[n];
            t = z * sigmoidf_(z);
          }
          sm[(lmb + r) * 132 + ln] = f2bf(t);
        }
      }
    }
    __syncthreads();
    int row = tid >> 1, half = tid & 1;
    const unsigned short* src = sm + row * 132 + half * 64;
    unsigned short* gptr;
    if (EPI == 0) {
      gptr = ((bn < 512) ? outU : (outG - 512)) + (size_t)(bm + row) * 512 + bn + half * 64;
    } else {
      gptr = outG + (size_t)(bm + row) * N + bn + half * 64;
    }
#pragma unroll
    for (int s = 0; s < 8; s++)
      *(short8*)(gptr + s * 8) = *(const short8*)(src + s * 8);
  }
}

// ---------------- Scan phase 1: per-chunk fwd/bwd aggregates ---------------
__global__ __launch_bounds__(512) void scan_phase1(const unsigned short* __restrict__ u,
    const float* __restrict__ decay, float* __restrict__ fa, float* __restrict__ ba) {
  int c = threadIdx.x, k = blockIdx.x;
  float d = decay[c];
  const unsigned short* up = u + (size_t)k * CHUNK * CDIM + c;
  float f = 0.f, bs = 0.f, p = 1.f;
#pragma unroll 8
  for (int t = 0; t < CHUNK; t++) {
    float v = bf2f(up[(size_t)t * CDIM]);
    f = d * f + v;
    bs += p * v;
    p *= d;
  }
  fa[(size_t)k * CDIM + c] = f;
  ba[(size_t)k * CDIM + c] = bs;
}

// ---------------- Scan phase 2: cross-chunk carries ------------------------
__global__ __launch_bounds__(256) void scan_phase2(const float* __restrict__ fa,
    const float* __restrict__ ba, const float* __restrict__ decayT,
    float* __restrict__ fc, float* __restrict__ bc) {
  int c = blockIdx.x * 256 + threadIdx.x;
  float dT = decayT[c];
  float run = 0.f;
#pragma unroll 8
  for (int k = 0; k < NCHUNK; k++) {
    fc[(size_t)k * CDIM + c] = run;
    run = dT * run + fa[(size_t)k * CDIM + c];
  }
  run = 0.f;
#pragma unroll 8
  for (int k = NCHUNK - 1; k >= 0; k--) {
    bc[(size_t)k * CDIM + c] = run;
    run = dT * run + ba[(size_t)k * CDIM + c];
  }
}

// ---------------- Scan phase 3: apply carries, combine, gate ---------------
__global__ __launch_bounds__(512) void scan_phase3(const unsigned short* __restrict__ u,
    const unsigned short* __restrict__ gate, const float* __restrict__ decay,
    const float* __restrict__ fc, const float* __restrict__ bc,
    unsigned short* __restrict__ state) {
  int c = threadIdx.x, k = blockIdx.x;
  float d = decay[c];
  size_t base = (size_t)k * CHUNK * CDIM + c;
  float fwd[CHUNK];
  float run = fc[(size_t)k * CDIM + c];
#pragma unroll
  for (int t = 0; t < CHUNK; t++) {
    run = d * run + bf2f(u[base + (size_t)t * CDIM]);
    fwd[t] = run;
  }
  float runb = bc[(size_t)k * CDIM + c];
#pragma unroll
  for (int t = CHUNK - 1; t >= 0; t--) {
    runb = d * runb + bf2f(u[base + (size_t)t * CDIM]);
    float g = bf2f(gate[base + (size_t)t * CDIM]);
    state[base + (size_t)t * CDIM] = f2bf(0.5f * (fwd[t] + runb) * g);
  }
}

// ---------------------------------------------------------------------------
extern "C" void kernel_launch(void* const* d_in, const int* in_sizes, int n_in,
                              void* d_out, int out_size, void* d_ws, size_t ws_size,
                              hipStream_t stream) {
  const float* x = (const float*)d_in[0];
  const float* ln1_w = (const float*)d_in[1];
  const float* ln1_b = (const float*)d_in[2];
  const float* W_in = (const float*)d_in[3];
  const float* b_in = (const float*)d_in[4];
  const float* W_gate = (const float*)d_in[5];
  const float* b_gate = (const float*)d_in[6];
  const float* W_out = (const float*)d_in[7];
  const float* b_out = (const float*)d_in[8];
  const float* decay_logit = (const float*)d_in[9];
  const float* ln2_w = (const float*)d_in[10];
  const float* ln2_b = (const float*)d_in[11];
  const float* W_ff1 = (const float*)d_in[12];
  const float* b_ff1 = (const float*)d_in[13];
  const float* W_ff2 = (const float*)d_in[14];
  const float* b_ff2 = (const float*)d_in[15];

  char* ws = (char*)d_ws;
  size_t off = 0;
  auto alloc = [&](size_t bytes) -> void* {
    void* p = ws + off;
    off += (bytes + 255) & ~(size_t)255;
    return p;
  };
  // --- small persistent buffers (~8.5 MB) ---
  unsigned short* Wt_ig  = (unsigned short*)alloc((size_t)1024 * 512 * 2);
  unsigned short* Wt_out = (unsigned short*)alloc((size_t)512 * 512 * 2);
  unsigned short* Wt_ff1 = (unsigned short*)alloc((size_t)1024 * 512 * 2);
  unsigned short* Wt_ff2 = (unsigned short*)alloc((size_t)512 * 1024 * 2);
  float* fa = (float*)alloc((size_t)NCHUNK * CDIM * 4);
  float* ba = (float*)alloc((size_t)NCHUNK * CDIM * 4);
  float* fc = (float*)alloc((size_t)NCHUNK * CDIM * 4);
  float* bc = (float*)alloc((size_t)NCHUNK * CDIM * 4);
  float* decay  = (float*)alloc(CDIM * 4);
  float* decayT = (float*)alloc(CDIM * 4);
  // --- large aliased regions (liveness-disjoint) ---
  const size_t LC2 = (size_t)L_SEQ * CDIM * 2; // 33.55 MB
  unsigned short* R1 = (unsigned short*)alloc(LC2);      // hidden -> state -> hbuf
  unsigned short* R2 = (unsigned short*)alloc(LC2);      // u(bf16) -> ffb[0:]
  unsigned short* R3 = (unsigned short*)alloc(LC2);      // gate    -> ffb[L*C:]
  unsigned short* hidden = R1;
  unsigned short* state  = R1;
  unsigned short* hbuf   = R1;
  unsigned short* u_buf  = R2;
  unsigned short* gate   = R3;
  unsigned short* ffb    = R2; // 67 MB spanning R2+R3 (contiguous)
  float* x2 = (float*)d_out;   // d_out doubles as x2 buffer

  // single prep launch: all transposes + decay
  prep_all<<<1793, 256, 0, stream>>>(W_in, W_gate, W_out, W_ff1, W_ff2,
      decay_logit, Wt_ig, Wt_out, Wt_ff1, Wt_ff2, decay, decayT);

  // LN1
  ln_kernel<<<L_SEQ / 4, 256, 0, stream>>>(x, ln1_w, ln1_b, hidden);

  // u | gate fused GEMM (N=1024); grid = (M/128, N/128)
  gemm_bt<0><<<dim3(L_SEQ / 128, 1024 / 128), 256, 0, stream>>>(
      hidden, Wt_ig, b_in, b_gate, nullptr, nullptr, u_buf, gate, L_SEQ, 1024, 512);

  // bidirectional scan
  scan_phase1<<<NCHUNK, 512, 0, stream>>>(u_buf, decay, fa, ba);
  scan_phase2<<<2, 256, 0, stream>>>(fa, ba, decayT, fc, bc);
  scan_phase3<<<NCHUNK, 512, 0, stream>>>(u_buf, gate, decay, fc, bc, state);

  // x2 = x + state @ W_out + b_out   (written to d_out)
  gemm_bt<1><<<dim3(L_SEQ / 128, 512 / 128), 256, 0, stream>>>(
      state, Wt_out, b_out, nullptr, x, x2, nullptr, nullptr, L_SEQ, 512, 512);

  // LN2
  ln_kernel<<<L_SEQ / 4, 256, 0, stream>>>(x2, ln2_w, ln2_b, hbuf);

  // ff = silu(h @ W_ff1 + b_ff1)
  gemm_bt<2><<<dim3(L_SEQ / 128, 1024 / 128), 256, 0, stream>>>(
      hbuf, Wt_ff1, b_ff1, nullptr, nullptr, nullptr, nullptr, ffb, L_SEQ, 1024, 512);

  // out = x2 + ff @ W_ff2 + b_ff2   (in-place read/write on d_out is per-element safe)
  gemm_bt<1><<<dim3(L_SEQ / 128, 512 / 128), 256, 0, stream>>>(
      ffb, Wt_ff2, b_ff2, nullptr, x2, x2, nullptr, nullptr, L_SEQ, 512, 1024);
}